// Round 3
// baseline (6493.674 us; speedup 1.0000x reference)
//
#include <hip/hip_runtime.h>
#include <hip/hip_bf16.h>

// Problem constants
#define BB 64
#define TT 256
#define HH 512
#define EE 256
#define NTAGS 50
#define BT (BB * TT)  // 16384

typedef _Float16 f16;
typedef __attribute__((ext_vector_type(2))) _Float16 half2v;
typedef __attribute__((ext_vector_type(4))) _Float16 half4;
typedef __attribute__((ext_vector_type(8))) _Float16 half8;
typedef __attribute__((ext_vector_type(8))) short short8;
typedef __attribute__((ext_vector_type(4))) float f32x4;
typedef __hip_bfloat16 bf16;

__device__ __forceinline__ float sigm(float x) {
    return 1.f / (1.f + __expf(-x));
}
__device__ __forceinline__ float tanh_f(float x) {
    float ax = fabsf(x);
    float e = __expf(2.f * ax);
    float t = 1.f - 2.f / (e + 1.f);
    return x < 0.f ? -t : t;
}
__device__ __forceinline__ short f2bs(float f) {
    return (short)__bfloat16_as_ushort(__float2bfloat16(f));
}
// split 8 fp32 values (in regs) into bf16 hi + bf16 lo(residual)
__device__ __forceinline__ void split8v(const float* vv, bf16* hi, bf16* lo) {
    short8 h8, l8;
#pragma unroll
    for (int j = 0; j < 8; ++j) {
        bf16 h = __float2bfloat16(vv[j]);
        h8[j] = (short)__bfloat16_as_ushort(h);
        l8[j] = f2bs(vv[j] - __bfloat162float(h));
    }
    *(short8*)hi = h8;
    *(short8*)lo = l8;
}
__device__ __forceinline__ void split8(const float* p, bf16* hi, bf16* lo) {
    float4 v0 = *(const float4*)p;
    float4 v1 = *(const float4*)(p + 4);
    float vv[8] = {v0.x, v0.y, v0.z, v0.w, v1.x, v1.y, v1.z, v1.w};
    split8v(vv, hi, lo);
}
__device__ __forceinline__ void split8h(const f16* p, bf16* hi, bf16* lo) {
    half8 a = *(const half8*)p;
    float vv[8];
#pragma unroll
    for (int j = 0; j < 8; ++j) vv[j] = (float)a[j];
    split8v(vv, hi, lo);
}

// ---------------------------------------------------------------------------
// 2 dirs x 32 flags x 16-int (64B) spacing = 1024 ints = 4KB
__global__ void bar_init(int* __restrict__ bar) {
    bar[blockIdx.x * 256 + threadIdx.x] = 0;
}

// ---------------------------------------------------------------------------
// embedding gather fp32 -> f16 storage
__global__ __launch_bounds__(256) void embed_gather(
    const int* __restrict__ x, const float* __restrict__ emb, f16* __restrict__ e) {
    int idx = blockIdx.x * 4 + (threadIdx.x >> 6);
    int lane = threadIdx.x & 63;
    int tok = x[idx];
    float4 v = *(const float4*)(emb + (size_t)tok * EE + lane * 4);
    half4 o;
    o[0] = (f16)v.x; o[1] = (f16)v.y; o[2] = (f16)v.z; o[3] = (f16)v.w;
    *(half4*)(e + (size_t)idx * EE + lane * 4) = o;
}

// ---------------------------------------------------------------------------
// C[M,N] = A[M,K] @ W[N,K]^T + bias[N].  A: f16 storage, W/bias fp32.
// Both split to bf16 hi+lo in LDS; 3 MFMA products -> ~fp32 accuracy. f16 out.
__global__ __launch_bounds__(256) void gemm_bt(
    const f16* __restrict__ A, const float* __restrict__ W,
    const float* __restrict__ bias, f16* __restrict__ C,
    int M, int N, int K) {
    __shared__ bf16 Ah[128][72], Al[128][72];
    __shared__ bf16 Wh[128][72], Wl[128][72];
    const int m0 = blockIdx.x * 128;
    const int n0 = blockIdx.y * 128;
    const int tid = threadIdx.x;
    const int wave = tid >> 6;
    const int lane = tid & 63;
    const int lrow = lane & 15;
    const int quad = lane >> 4;
    const int msub = (wave >> 1) * 64;
    const int nsub = (wave & 1) * 64;

    f32x4 acc[4][4];
#pragma unroll
    for (int i = 0; i < 4; ++i)
#pragma unroll
        for (int j = 0; j < 4; ++j) acc[i][j] = (f32x4){0.f, 0.f, 0.f, 0.f};

    for (int k0 = 0; k0 < K; k0 += 64) {
        __syncthreads();
#pragma unroll
        for (int c = 0; c < 4; ++c) {
            int f = c * 256 + tid;
            int row = f >> 3;
            int kc = f & 7;
            split8h(A + (size_t)(m0 + row) * K + k0 + kc * 8,
                    &Ah[row][kc * 8], &Al[row][kc * 8]);
            split8(W + (size_t)(n0 + row) * K + k0 + kc * 8,
                   &Wh[row][kc * 8], &Wl[row][kc * 8]);
        }
        __syncthreads();
#pragma unroll
        for (int ks = 0; ks < 2; ++ks) {
            short8 ah[4], al[4], bh[4], bl[4];
#pragma unroll
            for (int i = 0; i < 4; ++i) {
                ah[i] = *(const short8*)&Ah[msub + i * 16 + lrow][ks * 32 + quad * 8];
                al[i] = *(const short8*)&Al[msub + i * 16 + lrow][ks * 32 + quad * 8];
            }
#pragma unroll
            for (int j = 0; j < 4; ++j) {
                bh[j] = *(const short8*)&Wh[nsub + j * 16 + lrow][ks * 32 + quad * 8];
                bl[j] = *(const short8*)&Wl[nsub + j * 16 + lrow][ks * 32 + quad * 8];
            }
#pragma unroll
            for (int i = 0; i < 4; ++i)
#pragma unroll
                for (int j = 0; j < 4; ++j) {
                    acc[i][j] = __builtin_amdgcn_mfma_f32_16x16x32_bf16(ah[i], bh[j], acc[i][j], 0, 0, 0);
                    acc[i][j] = __builtin_amdgcn_mfma_f32_16x16x32_bf16(ah[i], bl[j], acc[i][j], 0, 0, 0);
                    acc[i][j] = __builtin_amdgcn_mfma_f32_16x16x32_bf16(al[i], bh[j], acc[i][j], 0, 0, 0);
                }
        }
    }

#pragma unroll
    for (int j = 0; j < 4; ++j) {
        int n = n0 + nsub + j * 16 + lrow;
        float bv = bias[n];
#pragma unroll
        for (int i = 0; i < 4; ++i)
#pragma unroll
            for (int r = 0; r < 4; ++r) {
                int m = m0 + msub + i * 16 + quad * 4 + r;
                C[(size_t)m * N + n] = (f16)(acc[i][j][r] + bv);
            }
    }
}

// ---------------------------------------------------------------------------
// Classifier: logits[BT,50] fp32 = out2[BT,1024] @ cls_w[50,1024]^T + cls_b.
__global__ __launch_bounds__(256) void cls_gemm(
    const f16* __restrict__ A, const float* __restrict__ W,
    const float* __restrict__ bias, float* __restrict__ C) {
    __shared__ bf16 Ah[128][72], Al[128][72];
    __shared__ bf16 Wh[64][72], Wl[64][72];
    const int m0 = blockIdx.x * 128;
    const int tid = threadIdx.x;
    const int wave = tid >> 6;
    const int lane = tid & 63;
    const int lrow = lane & 15;
    const int quad = lane >> 4;
    const int msub = wave * 32;

    f32x4 acc[2][4];
#pragma unroll
    for (int i = 0; i < 2; ++i)
#pragma unroll
        for (int j = 0; j < 4; ++j) acc[i][j] = (f32x4){0.f, 0.f, 0.f, 0.f};

    for (int k0 = 0; k0 < 1024; k0 += 64) {
        __syncthreads();
#pragma unroll
        for (int c = 0; c < 4; ++c) {
            int f = c * 256 + tid;
            int row = f >> 3;
            int kc = f & 7;
            split8h(A + (size_t)(m0 + row) * 1024 + k0 + kc * 8,
                    &Ah[row][kc * 8], &Al[row][kc * 8]);
        }
#pragma unroll
        for (int c = 0; c < 2; ++c) {
            int f = c * 256 + tid;
            int row = f >> 3;
            int kc = f & 7;
            int wr = row < NTAGS ? row : NTAGS - 1;
            split8(W + (size_t)wr * 1024 + k0 + kc * 8,
                   &Wh[row][kc * 8], &Wl[row][kc * 8]);
        }
        __syncthreads();
#pragma unroll
        for (int ks = 0; ks < 2; ++ks) {
            short8 ah[2], al[2], bh[4], bl[4];
#pragma unroll
            for (int i = 0; i < 2; ++i) {
                ah[i] = *(const short8*)&Ah[msub + i * 16 + lrow][ks * 32 + quad * 8];
                al[i] = *(const short8*)&Al[msub + i * 16 + lrow][ks * 32 + quad * 8];
            }
#pragma unroll
            for (int j = 0; j < 4; ++j) {
                bh[j] = *(const short8*)&Wh[j * 16 + lrow][ks * 32 + quad * 8];
                bl[j] = *(const short8*)&Wl[j * 16 + lrow][ks * 32 + quad * 8];
            }
#pragma unroll
            for (int i = 0; i < 2; ++i)
#pragma unroll
                for (int j = 0; j < 4; ++j) {
                    acc[i][j] = __builtin_amdgcn_mfma_f32_16x16x32_bf16(ah[i], bh[j], acc[i][j], 0, 0, 0);
                    acc[i][j] = __builtin_amdgcn_mfma_f32_16x16x32_bf16(ah[i], bl[j], acc[i][j], 0, 0, 0);
                    acc[i][j] = __builtin_amdgcn_mfma_f32_16x16x32_bf16(al[i], bh[j], acc[i][j], 0, 0, 0);
                }
        }
    }

#pragma unroll
    for (int j = 0; j < 4; ++j) {
        int n = j * 16 + lrow;
        if (n < NTAGS) {
            float bv = bias[n];
#pragma unroll
            for (int i = 0; i < 2; ++i)
#pragma unroll
                for (int r = 0; r < 4; ++r) {
                    int m = m0 + msub + i * 16 + quad * 4 + r;
                    C[(size_t)m * NTAGS + n] = acc[i][j][r] + bv;
                }
        }
    }
}

// ---------------------------------------------------------------------------
// Persistent masked BiLSTM scan — FAT BLOCKS (32/dir, 16 units each).
//
// R1/R2 finding: per-step time (~9us) is invariant to consumer-side load
// restructuring -> dominated by LLC op/traffic (every block re-reads ALL of
// h: 16 MB/step of cache-bypassing loads) and/or flag contention.  This
// version halves both: 32 blocks/dir each owning 16 hidden units (64 gate
// rows, 133KB LDS for the w_hh slice), so total h re-read traffic and sync
// participant count halve.  Flags become single-producer: the producer does
// ONE relaxed-agent atomic STORE of (base+s+1) (no RMW round trip); only
// wave 0 polls (2 lanes per flag), __syncthreads releases the block.
// Publish packs 4 units into ONE 8-byte atomic store per buffer.
//
// Safety: consumer reaches its step-s h-store only after wave0 saw all 32
// flags >= base+s (each implies that producer's step-(s-1) publish drained
// to LLC before its flag store), barrier-ordered for all waves -> no
// read/write overlap on the 2-deep parity buffer.  Same visibility chain
// as the harness-verified design: relaxed agent stores -> syncthreads
// (vmcnt drain) -> relaxed agent flag store.
__global__ __launch_bounds__(256) void lstm_scan(
    const f16* __restrict__ xpre_f, const f16* __restrict__ xpre_b,
    const float* __restrict__ whh_f, const float* __restrict__ whh_b,
    const int* __restrict__ lengths,
    f16* __restrict__ out,      // [BT, 2H]
    bf16* __restrict__ hbuf,    // [dir][parity][hi/lo][64][512]
    int* __restrict__ bar, int base) {
    __shared__ bf16 w_hi[64][520];   // 64 gate rows x 512, +8 pad (66.6KB)
    __shared__ bf16 w_lo[64][520];
    __shared__ float gat[64][65];    // [batch][gaterow g*16+u], pad->65
    __shared__ int len_s[64];

    const int dir = blockIdx.x >> 5;
    const int sl = blockIdx.x & 31;  // owns units [sl*16, sl*16+16)
    const int tid = threadIdx.x;
    const int wave = tid >> 6;
    const int lane = tid & 63;
    const int lrow = lane & 15;
    const int quad = lane >> 4;
    // gate-phase mapping: thread -> (batch gb, units u0..u0+3)
    const int gb = tid >> 2;
    const int up = tid & 3;
    const int u0 = up * 4;

    const f16* xpre = dir ? xpre_b : xpre_f;
    const float* whh = dir ? whh_b : whh_f;
    bf16* hb = hbuf + (size_t)dir * 2 * 2 * BB * HH;
    int* flags = bar + dir * 512;    // 32 single-producer flags, 64B apart
    int* myflag = flags + sl * 16;

    // stage w_hh slice rows r = g*16+u  <-  whh[g*512 + sl*16 + u][:], hi/lo
    for (int f = tid; f < 64 * 64; f += 256) {
        int row = f >> 6;
        int c8 = f & 63;
        int g = row >> 4, u = row & 15;
        split8(whh + (size_t)(g * HH + sl * 16 + u) * HH + c8 * 8,
               &w_hi[row][c8 * 8], &w_lo[row][c8 * 8]);
    }
    if (tid < 64) len_s[tid] = lengths[tid];
    __syncthreads();

    // persistent per-thread recurrent state (4 hidden units each)
    float hr[4] = {0.f, 0.f, 0.f, 0.f};
    float cr[4] = {0.f, 0.f, 0.f, 0.f};

    // prefetch xpre for s = 0 (len >= 1 always)
    float pr[4][4];  // [gate][unit j]
    {
        int len = len_s[gb];
        int ta = dir ? (len - 1) : 0;
        const f16* xp = xpre + (size_t)(gb * TT + ta) * 2048 + sl * 16 + u0;
#pragma unroll
        for (int g = 0; g < 4; ++g) {
            half4 v = *(const half4*)(xp + g * 512);
            pr[g][0] = (float)v[0]; pr[g][1] = (float)v[1];
            pr[g][2] = (float)v[2]; pr[g][3] = (float)v[3];
        }
    }

    for (int s = 0; s < TT; ++s) {
        if (s > 0) {
            const int target = base + s;
            const unsigned long long* hp_hi = (const unsigned long long*)
                (hb + (size_t)(((s & 1) ^ 1) * 2) * BB * HH);
            const unsigned long long* hp_lo = hp_hi + (BB * HH / 4);

            // ---- wave0-only vectorized readiness check (2 lanes per flag)
            if (wave == 0) {
                int* fp = &flags[(lane & 31) * 16];
                int v = __hip_atomic_load(fp, __ATOMIC_RELAXED,
                                          __HIP_MEMORY_SCOPE_AGENT);
                while (__ballot(v >= target) != ~0ull) {
                    __builtin_amdgcn_s_sleep(1);
                    v = __hip_atomic_load(fp, __ATOMIC_RELAXED,
                                          __HIP_MEMORY_SCOPE_AGENT);
                }
            }
            __syncthreads();
            __asm__ volatile("" ::: "memory");

            // ---- issue ALL h loads (64 x u64 per thread, static regs)
            const int b = wave * 16 + lrow;
            const int bofs = b * 128;  // u64 units per h-row = 512/4
            unsigned long long qh0[16], qh1[16], ql0[16], ql1[16];
#pragma unroll
            for (int c = 0; c < 16; ++c) {
                int idx = bofs + c * 8 + quad * 2;
                qh0[c] = __hip_atomic_load((unsigned long long*)&hp_hi[idx],
                                           __ATOMIC_RELAXED, __HIP_MEMORY_SCOPE_AGENT);
                qh1[c] = __hip_atomic_load((unsigned long long*)&hp_hi[idx + 1],
                                           __ATOMIC_RELAXED, __HIP_MEMORY_SCOPE_AGENT);
                ql0[c] = __hip_atomic_load((unsigned long long*)&hp_lo[idx],
                                           __ATOMIC_RELAXED, __HIP_MEMORY_SCOPE_AGENT);
                ql1[c] = __hip_atomic_load((unsigned long long*)&hp_lo[idx + 1],
                                           __ATOMIC_RELAXED, __HIP_MEMORY_SCOPE_AGENT);
            }

            // ---- MFMA chain: 4 nt tiles (= 4 gates) x 16 chunks x 3 products
            f32x4 acc[4];
#pragma unroll
            for (int nt = 0; nt < 4; ++nt) acc[nt] = (f32x4){0.f, 0.f, 0.f, 0.f};
#pragma unroll
            for (int c = 0; c < 16; ++c) {
                union { unsigned long long q[2]; short8 v; } ua, ul;
                ua.q[0] = qh0[c]; ua.q[1] = qh1[c];
                ul.q[0] = ql0[c]; ul.q[1] = ql1[c];
                short8 ahh = ua.v;
                short8 al_ = ul.v;
#pragma unroll
                for (int nt = 0; nt < 4; ++nt) {
                    short8 bhh = *(const short8*)&w_hi[nt * 16 + lrow][c * 32 + quad * 8];
                    short8 bll = *(const short8*)&w_lo[nt * 16 + lrow][c * 32 + quad * 8];
                    acc[nt] = __builtin_amdgcn_mfma_f32_16x16x32_bf16(ahh, bhh, acc[nt], 0, 0, 0);
                    acc[nt] = __builtin_amdgcn_mfma_f32_16x16x32_bf16(al_, bhh, acc[nt], 0, 0, 0);
                    acc[nt] = __builtin_amdgcn_mfma_f32_16x16x32_bf16(ahh, bll, acc[nt], 0, 0, 0);
                }
            }
#pragma unroll
            for (int nt = 0; nt < 4; ++nt)
#pragma unroll
                for (int r = 0; r < 4; ++r)
                    gat[wave * 16 + quad * 4 + r][nt * 16 + lrow] = acc[nt][r];
            __syncthreads();
        }

        // ---- gate phase: thread handles (gb, units u0..u0+3) ----
        unsigned long long* hc_hi = (unsigned long long*)
            (hb + (size_t)((s & 1) * 2) * BB * HH);
        unsigned long long* hc_lo = hc_hi + (BB * HH / 4);
        const int len = len_s[gb];
        const bool act = (s < len);
        if (act) {
#pragma unroll
            for (int j = 0; j < 4; ++j) {
                float zi = pr[0][j], zf = pr[1][j], zg = pr[2][j], zo = pr[3][j];
                if (s > 0) {
                    zi += gat[gb][u0 + j];
                    zf += gat[gb][16 + u0 + j];
                    zg += gat[gb][32 + u0 + j];
                    zo += gat[gb][48 + u0 + j];
                }
                float ii = sigm(zi), ff = sigm(zf);
                float gg = tanh_f(zg), oo = sigm(zo);
                cr[j] = ff * cr[j] + ii * gg;
                hr[j] = oo * tanh_f(cr[j]);
            }
        }
        // publish hi/lo packed (always; carried h for masked rows): one 8B
        // atomic store per buffer
        {
            unsigned long long hwq = 0ull, lwq = 0ull;
#pragma unroll
            for (int j = 0; j < 4; ++j) {
                bf16 bh = __float2bfloat16(hr[j]);
                unsigned short hs = __bfloat16_as_ushort(bh);
                unsigned short ls = (unsigned short)f2bs(hr[j] - __bfloat162float(bh));
                hwq |= (unsigned long long)hs << (16 * j);
                lwq |= (unsigned long long)ls << (16 * j);
            }
            int widx = gb * 128 + sl * 4 + up;  // u64 units per h-row = 128
            __hip_atomic_store(&hc_hi[widx], hwq, __ATOMIC_RELAXED,
                               __HIP_MEMORY_SCOPE_AGENT);
            __hip_atomic_store(&hc_lo[widx], lwq, __ATOMIC_RELAXED,
                               __HIP_MEMORY_SCOPE_AGENT);
        }
        __asm__ volatile("" ::: "memory");
        __syncthreads();  // drains vmcnt(0): all waves' h-stores globally visible

        // signal: one fire-and-forget atomic STORE per block (monotonic)
        if (tid == 0)
            __hip_atomic_store(myflag, base + s + 1, __ATOMIC_RELAXED,
                               __HIP_MEMORY_SCOPE_AGENT);

        // off the inter-block critical path: prefetch next xpre, then out store
        if (s + 1 < TT) {
            if (s + 1 < len) {
                int ta = dir ? (len - 2 - s) : (s + 1);
                const f16* xp = xpre + (size_t)(gb * TT + ta) * 2048 + sl * 16 + u0;
#pragma unroll
                for (int g = 0; g < 4; ++g) {
                    half4 v = *(const half4*)(xp + g * 512);
                    pr[g][0] = (float)v[0]; pr[g][1] = (float)v[1];
                    pr[g][2] = (float)v[2]; pr[g][3] = (float)v[3];
                }
            }
        }
        if (act) {
            int ta = dir ? (len - 1 - s) : s;
            half4 ov;
            ov[0] = (f16)hr[0]; ov[1] = (f16)hr[1];
            ov[2] = (f16)hr[2]; ov[3] = (f16)hr[3];
            *(half4*)(out + (size_t)(gb * TT + ta) * 1024 + dir * 512 + sl * 16 + u0) = ov;
        } else {
            half4 zv;
            zv[0] = (f16)0.f; zv[1] = (f16)0.f; zv[2] = (f16)0.f; zv[3] = (f16)0.f;
            *(half4*)(out + (size_t)(gb * TT + s) * 1024 + dir * 512 + sl * 16 + u0) = zv;
        }
    }
}

// ---------------------------------------------------------------------------
extern "C" void kernel_launch(void* const* d_in, const int* in_sizes, int n_in,
                              void* d_out, int out_size, void* d_ws, size_t ws_size,
                              hipStream_t stream) {
    const int* x = (const int*)d_in[0];
    const int* lengths = (const int*)d_in[1];
    const float* emb = (const float*)d_in[2];
    const float* w_ih_f1 = (const float*)d_in[3];
    const float* w_hh_f1 = (const float*)d_in[4];
    const float* b_f1 = (const float*)d_in[5];
    const float* w_ih_b1 = (const float*)d_in[6];
    const float* w_hh_b1 = (const float*)d_in[7];
    const float* b_b1 = (const float*)d_in[8];
    const float* w_ih_f2 = (const float*)d_in[9];
    const float* w_hh_f2 = (const float*)d_in[10];
    const float* b_f2 = (const float*)d_in[11];
    const float* w_ih_b2 = (const float*)d_in[12];
    const float* w_hh_b2 = (const float*)d_in[13];
    const float* b_b2 = (const float*)d_in[14];
    const float* cls_w = (const float*)d_in[15];
    const float* cls_b = (const float*)d_in[16];
    float* logits = (float*)d_out;

    // workspace layout (bytes) — max touched offset ~176 MB (proven envelope)
    char* ws = (char*)d_ws;
    int* bar = (int*)ws;                        // 0 .. 4 KB (2x32 flags, 64B apart)
    bf16* hbuf = (bf16*)(ws + 4096);            // 4 KB .. ~1.05 MB
    f16* e = (f16*)(ws + 2097152);              // 2 MB .. 10 MB
    f16* xpre_f = (f16*)(ws + 16777216);        // 16 MB .. 80 MB
    f16* xpre_b = (f16*)(ws + 83886080);        // 80 MB .. 144 MB
    f16* out1 = (f16*)(ws + 150994944);         // 144 MB .. 176 MB
    f16* out2 = out1;  // alias: out1 dead once layer-2 GEMMs complete

    bar_init<<<4, 256, 0, stream>>>(bar);
    embed_gather<<<BT / 4, 256, 0, stream>>>(x, emb, e);

    dim3 g1(BT / 128, 2048 / 128);
    gemm_bt<<<g1, 256, 0, stream>>>(e, w_ih_f1, b_f1, xpre_f, BT, 2048, EE);
    gemm_bt<<<g1, 256, 0, stream>>>(e, w_ih_b1, b_b1, xpre_b, BT, 2048, EE);
    lstm_scan<<<64, 256, 0, stream>>>(xpre_f, xpre_b, w_hh_f1, w_hh_b1,
                                      lengths, out1, hbuf, bar, 0);

    gemm_bt<<<g1, 256, 0, stream>>>(out1, w_ih_f2, b_f2, xpre_f, BT, 2048, 2 * HH);
    gemm_bt<<<g1, 256, 0, stream>>>(out1, w_ih_b2, b_b2, xpre_b, BT, 2048, 2 * HH);
    lstm_scan<<<64, 256, 0, stream>>>(xpre_f, xpre_b, w_hh_f2, w_hh_b2,
                                      lengths, out2, hbuf, bar, TT);

    cls_gemm<<<BT / 128, 256, 0, stream>>>(out2, cls_w, cls_b, logits);
}

// Round 4
// 4269.349 us; speedup vs baseline: 1.5210x; 1.5210x over previous
//
#include <hip/hip_runtime.h>
#include <hip/hip_bf16.h>

// Problem constants
#define BB 64
#define TT 256
#define HH 512
#define EE 256
#define NTAGS 50
#define BT (BB * TT)  // 16384

typedef _Float16 f16;
typedef __attribute__((ext_vector_type(2))) _Float16 half2v;
typedef __attribute__((ext_vector_type(4))) _Float16 half4;
typedef __attribute__((ext_vector_type(8))) _Float16 half8;
typedef __attribute__((ext_vector_type(8))) short short8;
typedef __attribute__((ext_vector_type(4))) float f32x4;
typedef __hip_bfloat16 bf16;

__device__ __forceinline__ float sigm(float x) {
    return 1.f / (1.f + __expf(-x));
}
__device__ __forceinline__ float tanh_f(float x) {
    float ax = fabsf(x);
    float e = __expf(2.f * ax);
    float t = 1.f - 2.f / (e + 1.f);
    return x < 0.f ? -t : t;
}
__device__ __forceinline__ short f2bs(float f) {
    return (short)__bfloat16_as_ushort(__float2bfloat16(f));
}
// split 8 fp32 values (in regs) into bf16 hi + bf16 lo(residual)
__device__ __forceinline__ void split8v(const float* vv, bf16* hi, bf16* lo) {
    short8 h8, l8;
#pragma unroll
    for (int j = 0; j < 8; ++j) {
        bf16 h = __float2bfloat16(vv[j]);
        h8[j] = (short)__bfloat16_as_ushort(h);
        l8[j] = f2bs(vv[j] - __bfloat162float(h));
    }
    *(short8*)hi = h8;
    *(short8*)lo = l8;
}
__device__ __forceinline__ void split8(const float* p, bf16* hi, bf16* lo) {
    float4 v0 = *(const float4*)p;
    float4 v1 = *(const float4*)(p + 4);
    float vv[8] = {v0.x, v0.y, v0.z, v0.w, v1.x, v1.y, v1.z, v1.w};
    split8v(vv, hi, lo);
}
__device__ __forceinline__ void split8h(const f16* p, bf16* hi, bf16* lo) {
    half8 a = *(const half8*)p;
    float vv[8];
#pragma unroll
    for (int j = 0; j < 8; ++j) vv[j] = (float)a[j];
    split8v(vv, hi, lo);
}

// ---------------------------------------------------------------------------
// 2 dirs x 64 flags x 16-int (64B) spacing = 2048 ints = 8KB
__global__ void bar_init(int* __restrict__ bar) {
    bar[blockIdx.x * 256 + threadIdx.x] = 0;
}

// ---------------------------------------------------------------------------
// embedding gather fp32 -> f16 storage
__global__ __launch_bounds__(256) void embed_gather(
    const int* __restrict__ x, const float* __restrict__ emb, f16* __restrict__ e) {
    int idx = blockIdx.x * 4 + (threadIdx.x >> 6);
    int lane = threadIdx.x & 63;
    int tok = x[idx];
    float4 v = *(const float4*)(emb + (size_t)tok * EE + lane * 4);
    half4 o;
    o[0] = (f16)v.x; o[1] = (f16)v.y; o[2] = (f16)v.z; o[3] = (f16)v.w;
    *(half4*)(e + (size_t)idx * EE + lane * 4) = o;
}

// ---------------------------------------------------------------------------
// C[M,N] = A[M,K] @ W[N,K]^T + bias[N].  A: f16 storage, W/bias fp32.
// Both split to bf16 hi+lo in LDS; 3 MFMA products -> ~fp32 accuracy. f16 out.
__global__ __launch_bounds__(256) void gemm_bt(
    const f16* __restrict__ A, const float* __restrict__ W,
    const float* __restrict__ bias, f16* __restrict__ C,
    int M, int N, int K) {
    __shared__ bf16 Ah[128][72], Al[128][72];
    __shared__ bf16 Wh[128][72], Wl[128][72];
    const int m0 = blockIdx.x * 128;
    const int n0 = blockIdx.y * 128;
    const int tid = threadIdx.x;
    const int wave = tid >> 6;
    const int lane = tid & 63;
    const int lrow = lane & 15;
    const int quad = lane >> 4;
    const int msub = (wave >> 1) * 64;
    const int nsub = (wave & 1) * 64;

    f32x4 acc[4][4];
#pragma unroll
    for (int i = 0; i < 4; ++i)
#pragma unroll
        for (int j = 0; j < 4; ++j) acc[i][j] = (f32x4){0.f, 0.f, 0.f, 0.f};

    for (int k0 = 0; k0 < K; k0 += 64) {
        __syncthreads();
#pragma unroll
        for (int c = 0; c < 4; ++c) {
            int f = c * 256 + tid;
            int row = f >> 3;
            int kc = f & 7;
            split8h(A + (size_t)(m0 + row) * K + k0 + kc * 8,
                    &Ah[row][kc * 8], &Al[row][kc * 8]);
            split8(W + (size_t)(n0 + row) * K + k0 + kc * 8,
                   &Wh[row][kc * 8], &Wl[row][kc * 8]);
        }
        __syncthreads();
#pragma unroll
        for (int ks = 0; ks < 2; ++ks) {
            short8 ah[4], al[4], bh[4], bl[4];
#pragma unroll
            for (int i = 0; i < 4; ++i) {
                ah[i] = *(const short8*)&Ah[msub + i * 16 + lrow][ks * 32 + quad * 8];
                al[i] = *(const short8*)&Al[msub + i * 16 + lrow][ks * 32 + quad * 8];
            }
#pragma unroll
            for (int j = 0; j < 4; ++j) {
                bh[j] = *(const short8*)&Wh[nsub + j * 16 + lrow][ks * 32 + quad * 8];
                bl[j] = *(const short8*)&Wl[nsub + j * 16 + lrow][ks * 32 + quad * 8];
            }
#pragma unroll
            for (int i = 0; i < 4; ++i)
#pragma unroll
                for (int j = 0; j < 4; ++j) {
                    acc[i][j] = __builtin_amdgcn_mfma_f32_16x16x32_bf16(ah[i], bh[j], acc[i][j], 0, 0, 0);
                    acc[i][j] = __builtin_amdgcn_mfma_f32_16x16x32_bf16(ah[i], bl[j], acc[i][j], 0, 0, 0);
                    acc[i][j] = __builtin_amdgcn_mfma_f32_16x16x32_bf16(al[i], bh[j], acc[i][j], 0, 0, 0);
                }
        }
    }

#pragma unroll
    for (int j = 0; j < 4; ++j) {
        int n = n0 + nsub + j * 16 + lrow;
        float bv = bias[n];
#pragma unroll
        for (int i = 0; i < 4; ++i)
#pragma unroll
            for (int r = 0; r < 4; ++r) {
                int m = m0 + msub + i * 16 + quad * 4 + r;
                C[(size_t)m * N + n] = (f16)(acc[i][j][r] + bv);
            }
    }
}

// ---------------------------------------------------------------------------
// Classifier: logits[BT,50] fp32 = out2[BT,1024] @ cls_w[50,1024]^T + cls_b.
__global__ __launch_bounds__(256) void cls_gemm(
    const f16* __restrict__ A, const float* __restrict__ W,
    const float* __restrict__ bias, float* __restrict__ C) {
    __shared__ bf16 Ah[128][72], Al[128][72];
    __shared__ bf16 Wh[64][72], Wl[64][72];
    const int m0 = blockIdx.x * 128;
    const int tid = threadIdx.x;
    const int wave = tid >> 6;
    const int lane = tid & 63;
    const int lrow = lane & 15;
    const int quad = lane >> 4;
    const int msub = wave * 32;

    f32x4 acc[2][4];
#pragma unroll
    for (int i = 0; i < 2; ++i)
#pragma unroll
        for (int j = 0; j < 4; ++j) acc[i][j] = (f32x4){0.f, 0.f, 0.f, 0.f};

    for (int k0 = 0; k0 < 1024; k0 += 64) {
        __syncthreads();
#pragma unroll
        for (int c = 0; c < 4; ++c) {
            int f = c * 256 + tid;
            int row = f >> 3;
            int kc = f & 7;
            split8h(A + (size_t)(m0 + row) * 1024 + k0 + kc * 8,
                    &Ah[row][kc * 8], &Al[row][kc * 8]);
        }
#pragma unroll
        for (int c = 0; c < 2; ++c) {
            int f = c * 256 + tid;
            int row = f >> 3;
            int kc = f & 7;
            int wr = row < NTAGS ? row : NTAGS - 1;
            split8(W + (size_t)wr * 1024 + k0 + kc * 8,
                   &Wh[row][kc * 8], &Wl[row][kc * 8]);
        }
        __syncthreads();
#pragma unroll
        for (int ks = 0; ks < 2; ++ks) {
            short8 ah[2], al[2], bh[4], bl[4];
#pragma unroll
            for (int i = 0; i < 2; ++i) {
                ah[i] = *(const short8*)&Ah[msub + i * 16 + lrow][ks * 32 + quad * 8];
                al[i] = *(const short8*)&Al[msub + i * 16 + lrow][ks * 32 + quad * 8];
            }
#pragma unroll
            for (int j = 0; j < 4; ++j) {
                bh[j] = *(const short8*)&Wh[j * 16 + lrow][ks * 32 + quad * 8];
                bl[j] = *(const short8*)&Wl[j * 16 + lrow][ks * 32 + quad * 8];
            }
#pragma unroll
            for (int i = 0; i < 2; ++i)
#pragma unroll
                for (int j = 0; j < 4; ++j) {
                    acc[i][j] = __builtin_amdgcn_mfma_f32_16x16x32_bf16(ah[i], bh[j], acc[i][j], 0, 0, 0);
                    acc[i][j] = __builtin_amdgcn_mfma_f32_16x16x32_bf16(ah[i], bl[j], acc[i][j], 0, 0, 0);
                    acc[i][j] = __builtin_amdgcn_mfma_f32_16x16x32_bf16(al[i], bh[j], acc[i][j], 0, 0, 0);
                }
        }
    }

#pragma unroll
    for (int j = 0; j < 4; ++j) {
        int n = j * 16 + lrow;
        if (n < NTAGS) {
            float bv = bias[n];
#pragma unroll
            for (int i = 0; i < 2; ++i)
#pragma unroll
                for (int r = 0; r < 4; ++r) {
                    int m = m0 + msub + i * 16 + quad * 4 + r;
                    C[(size_t)m * NTAGS + n] = acc[i][j][r] + bv;
                }
        }
    }
}

// ---------------------------------------------------------------------------
// Persistent masked BiLSTM scan — NON-ATOMIC sc0/sc1 WIDE DATA PATH.
//
// R1-R3 finding: per-step time (~9-11us) is invariant to sync scheduling
// AND to traffic volume -> suspect the 8B __hip_atomic_* bulk data path
// itself (conservative lowering, no 16B coalescing).  This version keeps
// the exact same memory behavior (bypass L1+L2, LLC-coherent) but uses
// plain inline-asm global_load_dwordx4 / global_store_dword with sc0 sc1:
//  - consumer: 32x16B loads issued as one burst, counted s_waitcnt
//    vmcnt(16)/vmcnt(0) + sched_barrier(0) so MFMA overlaps the tail;
//  - producer: 2x4B sc0sc1 stores, explicit vmcnt(0) drain before the
//    flag store.
// Shape back to R1's proven 128-block / 2-blocks-per-CU config (R3's
// 1 wave/SIMD exposed MFMA dependency latency).  Flags: 64/dir (one per
// block, 64B apart), single-producer monotonic atomic STORE; consumers
// poll one-lane-per-flag with a ballot.
//
// Safety: block reaches its step-s h-store (parity s&1) only after its
// ballot saw all 64 flags >= base+s, i.e. every same-dir block finished
// step-(s-1), whose reads (parity s&1) completed before its gat stores.
// Producer data stores are DRAINED (vmcnt(0)) before the flag store, so
// flag visibility implies data visibility at the coherence point.
__global__ __launch_bounds__(256) void lstm_scan(
    const f16* __restrict__ xpre_f, const f16* __restrict__ xpre_b,
    const float* __restrict__ whh_f, const float* __restrict__ whh_b,
    const int* __restrict__ lengths,
    f16* __restrict__ out,      // [BT, 2H]
    bf16* __restrict__ hbuf,    // [dir][parity][hi/lo][64][512]
    int* __restrict__ bar, int base) {
    __shared__ bf16 w_hi[32][520];   // 32 gate rows x 512, +8 pad
    __shared__ bf16 w_lo[32][520];
    __shared__ float gat[64][33];    // [batch][gate*8+u], stride 33 (conflict pad)
    __shared__ int len_s[64];

    const int dir = blockIdx.x >> 6;
    const int sl = blockIdx.x & 63;
    const int tid = threadIdx.x;
    const int wave = tid >> 6;
    const int lane = tid & 63;
    const int lrow = lane & 15;
    const int quad = lane >> 4;
    // gate-phase mapping: thread -> (batch, unit-pair)
    const int gb = tid >> 2;
    const int up = tid & 3;
    const int u0 = up * 2;

    const f16* xpre = dir ? xpre_b : xpre_f;
    const float* whh = dir ? whh_b : whh_f;
    bf16* hb = hbuf + (size_t)dir * 2 * 2 * BB * HH;
    int* flags = bar + dir * 1024;   // 64 single-producer flags, 64B apart
    int* myflag = flags + sl * 16;

    // stage w_hh slice rows r = g*8+u  <-  whh[g*512 + sl*8 + u][:], hi/lo
    for (int f = tid; f < 32 * 64; f += 256) {
        int row = f >> 6;
        int c = f & 63;
        int g = row >> 3, u = row & 7;
        split8(whh + (size_t)(g * HH + sl * 8 + u) * HH + c * 8,
               &w_hi[row][c * 8], &w_lo[row][c * 8]);
    }
    if (tid < 64) len_s[tid] = lengths[tid];
    __syncthreads();

    // persistent per-thread recurrent state (2 hidden units each)
    float hr0 = 0.f, hr1 = 0.f, cr0 = 0.f, cr1 = 0.f;

    // prefetch xpre for s = 0 (len >= 1 always)
    float pr[2][4];
    {
        int len = len_s[gb];
        int ta = dir ? (len - 1) : 0;
        const f16* xp = xpre + (size_t)(gb * TT + ta) * 2048 + sl * 8 + u0;
        half2v g0 = *(const half2v*)(xp);
        half2v g1 = *(const half2v*)(xp + 512);
        half2v g2 = *(const half2v*)(xp + 1024);
        half2v g3 = *(const half2v*)(xp + 1536);
        pr[0][0] = (float)g0[0]; pr[1][0] = (float)g0[1];
        pr[0][1] = (float)g1[0]; pr[1][1] = (float)g1[1];
        pr[0][2] = (float)g2[0]; pr[1][2] = (float)g2[1];
        pr[0][3] = (float)g3[0]; pr[1][3] = (float)g3[1];
    }

    for (int s = 0; s < TT; ++s) {
        if (s > 0) {
            const int target = base + s;

            // ---- readiness: lane L watches flag L; one ballot per poll
            {
                int* fp = &flags[lane * 16];
                int v = __hip_atomic_load(fp, __ATOMIC_RELAXED,
                                          __HIP_MEMORY_SCOPE_AGENT);
                while (__ballot(v >= target) != ~0ull) {
                    __builtin_amdgcn_s_sleep(1);
                    v = __hip_atomic_load(fp, __ATOMIC_RELAXED,
                                          __HIP_MEMORY_SCOPE_AGENT);
                }
            }
            __asm__ volatile("" ::: "memory");

            // ---- burst-issue ALL h loads: 32 x dwordx4, sc0 sc1
            const int b = wave * 16 + lrow;
            const char* hpb = (const char*)hb +
                (size_t)(((s & 1) ^ 1) * 2) * BB * HH * sizeof(bf16);
            const char* hib = hpb + b * 1024 + quad * 16;
            const char* lob = hib + BB * HH * sizeof(bf16);  // +64KB

            short8 AH[16], AL[16];
#pragma unroll
            for (int c = 0; c < 16; ++c) {
                asm volatile("global_load_dwordx4 %0, %1, off offset:%2 sc0 sc1"
                             : "=v"(AH[c]) : "v"(hib), "n"(c * 64));
                asm volatile("global_load_dwordx4 %0, %1, off offset:%2 sc0 sc1"
                             : "=v"(AL[c]) : "v"(lob), "n"(c * 64));
            }

            f32x4 acc[2];
            acc[0] = (f32x4){0.f, 0.f, 0.f, 0.f};
            acc[1] = (f32x4){0.f, 0.f, 0.f, 0.f};

            // first half ready at vmcnt(16) (in-order completion counting)
            asm volatile("s_waitcnt vmcnt(16)" ::: "memory");
            __builtin_amdgcn_sched_barrier(0);
#pragma unroll
            for (int c = 0; c < 8; ++c) {
#pragma unroll
                for (int nt = 0; nt < 2; ++nt) {
                    short8 bhh = *(const short8*)&w_hi[nt * 16 + lrow][c * 32 + quad * 8];
                    short8 bll = *(const short8*)&w_lo[nt * 16 + lrow][c * 32 + quad * 8];
                    acc[nt] = __builtin_amdgcn_mfma_f32_16x16x32_bf16(AH[c], bhh, acc[nt], 0, 0, 0);
                    acc[nt] = __builtin_amdgcn_mfma_f32_16x16x32_bf16(AL[c], bhh, acc[nt], 0, 0, 0);
                    acc[nt] = __builtin_amdgcn_mfma_f32_16x16x32_bf16(AH[c], bll, acc[nt], 0, 0, 0);
                }
            }
            asm volatile("s_waitcnt vmcnt(0)" ::: "memory");
            __builtin_amdgcn_sched_barrier(0);
#pragma unroll
            for (int c = 8; c < 16; ++c) {
#pragma unroll
                for (int nt = 0; nt < 2; ++nt) {
                    short8 bhh = *(const short8*)&w_hi[nt * 16 + lrow][c * 32 + quad * 8];
                    short8 bll = *(const short8*)&w_lo[nt * 16 + lrow][c * 32 + quad * 8];
                    acc[nt] = __builtin_amdgcn_mfma_f32_16x16x32_bf16(AH[c], bhh, acc[nt], 0, 0, 0);
                    acc[nt] = __builtin_amdgcn_mfma_f32_16x16x32_bf16(AL[c], bhh, acc[nt], 0, 0, 0);
                    acc[nt] = __builtin_amdgcn_mfma_f32_16x16x32_bf16(AH[c], bll, acc[nt], 0, 0, 0);
                }
            }
#pragma unroll
            for (int nt = 0; nt < 2; ++nt)
#pragma unroll
                for (int r = 0; r < 4; ++r)
                    gat[wave * 16 + quad * 4 + r][nt * 16 + lrow] = acc[nt][r];
            __syncthreads();
        }

        // ---- gate phase: thread handles (gb, units u0,u0+1) ----
        const int len = len_s[gb];
        const bool act = (s < len);
        if (act) {
            float z0[4], z1[4];
#pragma unroll
            for (int g = 0; g < 4; ++g) { z0[g] = pr[0][g]; z1[g] = pr[1][g]; }
            if (s > 0) {
#pragma unroll
                for (int g = 0; g < 4; ++g) {
                    z0[g] += gat[gb][g * 8 + u0];
                    z1[g] += gat[gb][g * 8 + u0 + 1];
                }
            }
            float i0 = sigm(z0[0]), f0 = sigm(z0[1]);
            float g0 = tanh_f(z0[2]), o0 = sigm(z0[3]);
            float i1 = sigm(z1[0]), f1 = sigm(z1[1]);
            float g1 = tanh_f(z1[2]), o1 = sigm(z1[3]);
            cr0 = f0 * cr0 + i0 * g0;
            cr1 = f1 * cr1 + i1 * g1;
            hr0 = o0 * tanh_f(cr0);
            hr1 = o1 * tanh_f(cr1);
        }
        // publish hi/lo packed (always; carried h for masked rows): 4B sc0sc1
        {
            bf16 bh0 = __float2bfloat16(hr0);
            bf16 bh1 = __float2bfloat16(hr1);
            unsigned int hw = (unsigned int)__bfloat16_as_ushort(bh0) |
                              ((unsigned int)__bfloat16_as_ushort(bh1) << 16);
            float r0 = hr0 - __bfloat162float(bh0);
            float r1 = hr1 - __bfloat162float(bh1);
            unsigned int lw = (unsigned int)(unsigned short)f2bs(r0) |
                              ((unsigned int)(unsigned short)f2bs(r1) << 16);
            char* hcb = (char*)hb + (size_t)((s & 1) * 2) * BB * HH * sizeof(bf16);
            char* pa = hcb + gb * 1024 + (sl * 8 + u0) * 2;
            char* pb = pa + BB * HH * sizeof(bf16);
            asm volatile("global_store_dword %0, %1, off sc0 sc1"
                         :: "v"(pa), "v"(hw) : "memory");
            asm volatile("global_store_dword %0, %1, off sc0 sc1"
                         :: "v"(pb), "v"(lw) : "memory");
        }
        asm volatile("s_waitcnt vmcnt(0)" ::: "memory");  // drain h-stores
        __syncthreads();

        // signal: one fire-and-forget monotonic atomic STORE per block
        if (tid == 0)
            __hip_atomic_store(myflag, base + s + 1, __ATOMIC_RELAXED,
                               __HIP_MEMORY_SCOPE_AGENT);

        // off the inter-block critical path: prefetch next xpre, then out store
        if (s + 1 < TT) {
            if (s + 1 < len) {
                int ta = dir ? (len - 2 - s) : (s + 1);
                const f16* xp = xpre + (size_t)(gb * TT + ta) * 2048 + sl * 8 + u0;
                half2v g0 = *(const half2v*)(xp);
                half2v g1 = *(const half2v*)(xp + 512);
                half2v g2 = *(const half2v*)(xp + 1024);
                half2v g3 = *(const half2v*)(xp + 1536);
                pr[0][0] = (float)g0[0]; pr[1][0] = (float)g0[1];
                pr[0][1] = (float)g1[0]; pr[1][1] = (float)g1[1];
                pr[0][2] = (float)g2[0]; pr[1][2] = (float)g2[1];
                pr[0][3] = (float)g3[0]; pr[1][3] = (float)g3[1];
            }
        }
        if (act) {
            int ta = dir ? (len - 1 - s) : s;
            half2v ov; ov[0] = (f16)hr0; ov[1] = (f16)hr1;
            *(half2v*)(out + (size_t)(gb * TT + ta) * 1024 + dir * 512 + sl * 8 + u0) = ov;
        } else {
            half2v zv; zv[0] = (f16)0.f; zv[1] = (f16)0.f;
            *(half2v*)(out + (size_t)(gb * TT + s) * 1024 + dir * 512 + sl * 8 + u0) = zv;
        }
    }
}

// ---------------------------------------------------------------------------
extern "C" void kernel_launch(void* const* d_in, const int* in_sizes, int n_in,
                              void* d_out, int out_size, void* d_ws, size_t ws_size,
                              hipStream_t stream) {
    const int* x = (const int*)d_in[0];
    const int* lengths = (const int*)d_in[1];
    const float* emb = (const float*)d_in[2];
    const float* w_ih_f1 = (const float*)d_in[3];
    const float* w_hh_f1 = (const float*)d_in[4];
    const float* b_f1 = (const float*)d_in[5];
    const float* w_ih_b1 = (const float*)d_in[6];
    const float* w_hh_b1 = (const float*)d_in[7];
    const float* b_b1 = (const float*)d_in[8];
    const float* w_ih_f2 = (const float*)d_in[9];
    const float* w_hh_f2 = (const float*)d_in[10];
    const float* b_f2 = (const float*)d_in[11];
    const float* w_ih_b2 = (const float*)d_in[12];
    const float* w_hh_b2 = (const float*)d_in[13];
    const float* b_b2 = (const float*)d_in[14];
    const float* cls_w = (const float*)d_in[15];
    const float* cls_b = (const float*)d_in[16];
    float* logits = (float*)d_out;

    // workspace layout (bytes) — max touched offset ~176 MB (proven envelope)
    char* ws = (char*)d_ws;
    int* bar = (int*)ws;                        // 0 .. 8 KB (2x64 flags, 64B apart)
    bf16* hbuf = (bf16*)(ws + 16384);           // 16 KB .. ~1.06 MB
    f16* e = (f16*)(ws + 2097152);              // 2 MB .. 10 MB
    f16* xpre_f = (f16*)(ws + 16777216);        // 16 MB .. 80 MB
    f16* xpre_b = (f16*)(ws + 83886080);        // 80 MB .. 144 MB
    f16* out1 = (f16*)(ws + 150994944);         // 144 MB .. 176 MB
    f16* out2 = out1;  // alias: out1 dead once layer-2 GEMMs complete

    bar_init<<<8, 256, 0, stream>>>(bar);
    embed_gather<<<BT / 4, 256, 0, stream>>>(x, emb, e);

    dim3 g1(BT / 128, 2048 / 128);
    gemm_bt<<<g1, 256, 0, stream>>>(e, w_ih_f1, b_f1, xpre_f, BT, 2048, EE);
    gemm_bt<<<g1, 256, 0, stream>>>(e, w_ih_b1, b_b1, xpre_b, BT, 2048, EE);
    lstm_scan<<<128, 256, 0, stream>>>(xpre_f, xpre_b, w_hh_f1, w_hh_b1,
                                       lengths, out1, hbuf, bar, 0);

    gemm_bt<<<g1, 256, 0, stream>>>(out1, w_ih_f2, b_f2, xpre_f, BT, 2048, 2 * HH);
    gemm_bt<<<g1, 256, 0, stream>>>(out1, w_ih_b2, b_b2, xpre_b, BT, 2048, 2 * HH);
    lstm_scan<<<128, 256, 0, stream>>>(xpre_f, xpre_b, w_hh_f2, w_hh_b2,
                                       lengths, out2, hbuf, bar, TT);

    cls_gemm<<<BT / 128, 256, 0, stream>>>(out2, cls_w, cls_b, logits);
}

// Round 5
// 4001.275 us; speedup vs baseline: 1.6229x; 1.0670x over previous
//
#include <hip/hip_runtime.h>
#include <hip/hip_bf16.h>

// Problem constants
#define BB 64
#define TT 256
#define HH 512
#define EE 256
#define NTAGS 50
#define BT (BB * TT)  // 16384

typedef _Float16 f16;
typedef __attribute__((ext_vector_type(2))) _Float16 half2v;
typedef __attribute__((ext_vector_type(4))) _Float16 half4;
typedef __attribute__((ext_vector_type(8))) _Float16 half8;
typedef __attribute__((ext_vector_type(8))) short short8;
typedef __attribute__((ext_vector_type(4))) float f32x4;
typedef __hip_bfloat16 bf16;

__device__ __forceinline__ float sigm(float x) {
    return 1.f / (1.f + __expf(-x));
}
__device__ __forceinline__ float tanh_f(float x) {
    float ax = fabsf(x);
    float e = __expf(2.f * ax);
    float t = 1.f - 2.f / (e + 1.f);
    return x < 0.f ? -t : t;
}
__device__ __forceinline__ short f2bs(float f) {
    return (short)__bfloat16_as_ushort(__float2bfloat16(f));
}
// split 8 fp32 values (in regs) into bf16 hi + bf16 lo(residual)
__device__ __forceinline__ void split8v(const float* vv, bf16* hi, bf16* lo) {
    short8 h8, l8;
#pragma unroll
    for (int j = 0; j < 8; ++j) {
        bf16 h = __float2bfloat16(vv[j]);
        h8[j] = (short)__bfloat16_as_ushort(h);
        l8[j] = f2bs(vv[j] - __bfloat162float(h));
    }
    *(short8*)hi = h8;
    *(short8*)lo = l8;
}
__device__ __forceinline__ void split8(const float* p, bf16* hi, bf16* lo) {
    float4 v0 = *(const float4*)p;
    float4 v1 = *(const float4*)(p + 4);
    float vv[8] = {v0.x, v0.y, v0.z, v0.w, v1.x, v1.y, v1.z, v1.w};
    split8v(vv, hi, lo);
}
__device__ __forceinline__ void split8h(const f16* p, bf16* hi, bf16* lo) {
    half8 a = *(const half8*)p;
    float vv[8];
#pragma unroll
    for (int j = 0; j < 8; ++j) vv[j] = (float)a[j];
    split8v(vv, hi, lo);
}

// ---------------------------------------------------------------------------
// 2 dirs x 64 flags x 16-int (64B) spacing = 2048 ints = 8KB
__global__ void bar_init(int* __restrict__ bar) {
    bar[blockIdx.x * 256 + threadIdx.x] = 0;
}

// ---------------------------------------------------------------------------
// embedding gather fp32 -> f16 storage
__global__ __launch_bounds__(256) void embed_gather(
    const int* __restrict__ x, const float* __restrict__ emb, f16* __restrict__ e) {
    int idx = blockIdx.x * 4 + (threadIdx.x >> 6);
    int lane = threadIdx.x & 63;
    int tok = x[idx];
    float4 v = *(const float4*)(emb + (size_t)tok * EE + lane * 4);
    half4 o;
    o[0] = (f16)v.x; o[1] = (f16)v.y; o[2] = (f16)v.z; o[3] = (f16)v.w;
    *(half4*)(e + (size_t)idx * EE + lane * 4) = o;
}

// ---------------------------------------------------------------------------
// C[M,N] = A[M,K] @ W[N,K]^T + bias[N].  A: f16 storage, W/bias fp32.
// Both split to bf16 hi+lo in LDS; 3 MFMA products -> ~fp32 accuracy. f16 out.
__global__ __launch_bounds__(256) void gemm_bt(
    const f16* __restrict__ A, const float* __restrict__ W,
    const float* __restrict__ bias, f16* __restrict__ C,
    int M, int N, int K) {
    __shared__ bf16 Ah[128][72], Al[128][72];
    __shared__ bf16 Wh[128][72], Wl[128][72];
    const int m0 = blockIdx.x * 128;
    const int n0 = blockIdx.y * 128;
    const int tid = threadIdx.x;
    const int wave = tid >> 6;
    const int lane = tid & 63;
    const int lrow = lane & 15;
    const int quad = lane >> 4;
    const int msub = (wave >> 1) * 64;
    const int nsub = (wave & 1) * 64;

    f32x4 acc[4][4];
#pragma unroll
    for (int i = 0; i < 4; ++i)
#pragma unroll
        for (int j = 0; j < 4; ++j) acc[i][j] = (f32x4){0.f, 0.f, 0.f, 0.f};

    for (int k0 = 0; k0 < K; k0 += 64) {
        __syncthreads();
#pragma unroll
        for (int c = 0; c < 4; ++c) {
            int f = c * 256 + tid;
            int row = f >> 3;
            int kc = f & 7;
            split8h(A + (size_t)(m0 + row) * K + k0 + kc * 8,
                    &Ah[row][kc * 8], &Al[row][kc * 8]);
            split8(W + (size_t)(n0 + row) * K + k0 + kc * 8,
                   &Wh[row][kc * 8], &Wl[row][kc * 8]);
        }
        __syncthreads();
#pragma unroll
        for (int ks = 0; ks < 2; ++ks) {
            short8 ah[4], al[4], bh[4], bl[4];
#pragma unroll
            for (int i = 0; i < 4; ++i) {
                ah[i] = *(const short8*)&Ah[msub + i * 16 + lrow][ks * 32 + quad * 8];
                al[i] = *(const short8*)&Al[msub + i * 16 + lrow][ks * 32 + quad * 8];
            }
#pragma unroll
            for (int j = 0; j < 4; ++j) {
                bh[j] = *(const short8*)&Wh[nsub + j * 16 + lrow][ks * 32 + quad * 8];
                bl[j] = *(const short8*)&Wl[nsub + j * 16 + lrow][ks * 32 + quad * 8];
            }
#pragma unroll
            for (int i = 0; i < 4; ++i)
#pragma unroll
                for (int j = 0; j < 4; ++j) {
                    acc[i][j] = __builtin_amdgcn_mfma_f32_16x16x32_bf16(ah[i], bh[j], acc[i][j], 0, 0, 0);
                    acc[i][j] = __builtin_amdgcn_mfma_f32_16x16x32_bf16(ah[i], bl[j], acc[i][j], 0, 0, 0);
                    acc[i][j] = __builtin_amdgcn_mfma_f32_16x16x32_bf16(al[i], bh[j], acc[i][j], 0, 0, 0);
                }
        }
    }

#pragma unroll
    for (int j = 0; j < 4; ++j) {
        int n = n0 + nsub + j * 16 + lrow;
        float bv = bias[n];
#pragma unroll
        for (int i = 0; i < 4; ++i)
#pragma unroll
            for (int r = 0; r < 4; ++r) {
                int m = m0 + msub + i * 16 + quad * 4 + r;
                C[(size_t)m * N + n] = (f16)(acc[i][j][r] + bv);
            }
    }
}

// ---------------------------------------------------------------------------
// Classifier: logits[BT,50] fp32 = out2[BT,1024] @ cls_w[50,1024]^T + cls_b.
__global__ __launch_bounds__(256) void cls_gemm(
    const f16* __restrict__ A, const float* __restrict__ W,
    const float* __restrict__ bias, float* __restrict__ C) {
    __shared__ bf16 Ah[128][72], Al[128][72];
    __shared__ bf16 Wh[64][72], Wl[64][72];
    const int m0 = blockIdx.x * 128;
    const int tid = threadIdx.x;
    const int wave = tid >> 6;
    const int lane = tid & 63;
    const int lrow = lane & 15;
    const int quad = lane >> 4;
    const int msub = wave * 32;

    f32x4 acc[2][4];
#pragma unroll
    for (int i = 0; i < 2; ++i)
#pragma unroll
        for (int j = 0; j < 4; ++j) acc[i][j] = (f32x4){0.f, 0.f, 0.f, 0.f};

    for (int k0 = 0; k0 < 1024; k0 += 64) {
        __syncthreads();
#pragma unroll
        for (int c = 0; c < 4; ++c) {
            int f = c * 256 + tid;
            int row = f >> 3;
            int kc = f & 7;
            split8h(A + (size_t)(m0 + row) * 1024 + k0 + kc * 8,
                    &Ah[row][kc * 8], &Al[row][kc * 8]);
        }
#pragma unroll
        for (int c = 0; c < 2; ++c) {
            int f = c * 256 + tid;
            int row = f >> 3;
            int kc = f & 7;
            int wr = row < NTAGS ? row : NTAGS - 1;
            split8(W + (size_t)wr * 1024 + k0 + kc * 8,
                   &Wh[row][kc * 8], &Wl[row][kc * 8]);
        }
        __syncthreads();
#pragma unroll
        for (int ks = 0; ks < 2; ++ks) {
            short8 ah[2], al[2], bh[4], bl[4];
#pragma unroll
            for (int i = 0; i < 2; ++i) {
                ah[i] = *(const short8*)&Ah[msub + i * 16 + lrow][ks * 32 + quad * 8];
                al[i] = *(const short8*)&Al[msub + i * 16 + lrow][ks * 32 + quad * 8];
            }
#pragma unroll
            for (int j = 0; j < 4; ++j) {
                bh[j] = *(const short8*)&Wh[j * 16 + lrow][ks * 32 + quad * 8];
                bl[j] = *(const short8*)&Wl[j * 16 + lrow][ks * 32 + quad * 8];
            }
#pragma unroll
            for (int i = 0; i < 2; ++i)
#pragma unroll
                for (int j = 0; j < 4; ++j) {
                    acc[i][j] = __builtin_amdgcn_mfma_f32_16x16x32_bf16(ah[i], bh[j], acc[i][j], 0, 0, 0);
                    acc[i][j] = __builtin_amdgcn_mfma_f32_16x16x32_bf16(ah[i], bl[j], acc[i][j], 0, 0, 0);
                    acc[i][j] = __builtin_amdgcn_mfma_f32_16x16x32_bf16(al[i], bh[j], acc[i][j], 0, 0, 0);
                }
        }
    }

#pragma unroll
    for (int j = 0; j < 4; ++j) {
        int n = j * 16 + lrow;
        if (n < NTAGS) {
            float bv = bias[n];
#pragma unroll
            for (int i = 0; i < 2; ++i)
#pragma unroll
                for (int r = 0; r < 4; ++r) {
                    int m = m0 + msub + i * 16 + quad * 4 + r;
                    C[(size_t)m * NTAGS + n] = acc[i][j][r] + bv;
                }
        }
    }
}

// ---------------------------------------------------------------------------
// Persistent masked BiLSTM scan — R4 protocol + 3 latency cuts:
//  1. w-hi operand in REGISTERS (128 VGPR; 1 wave/SIMD so VGPRs are free),
//     w-lo in lane-private LDS [slot][lane] (each lane reads back its own
//     writes; natural-minimum b128 banking) -> kills the ~8-way-conflicted
//     [32][520] ds_read_b128 pattern (was ~1180 cy/block/step).
//  2. wave0-only flag poll + __syncthreads release (4x less poll flood on
//     the LLC fabric that also carries the flag store and h bursts).
//  3. wave-LOCAL gate phase: wave w computes gat rows for batches
//     [16w,16w+16) and consumes only those -> the post-MFMA block barrier
//     is replaced by s_waitcnt lgkmcnt(0) + sched_barrier(0) (rule #18).
//     4 accumulator chains (nt x even/odd chunk) halve MFMA dep depth.
//
// Protocol (unchanged from R4, harness-verified): producers publish h with
// sc0sc1 dword stores, drain vmcnt(0), block barrier, tid0 stores the
// monotonic per-block flag (relaxed agent).  Consumer wave0 polls all 64
// flags (one lane each, ballot), barrier releases the block, then all
// waves burst-load h with sc0sc1 dwordx4 + counted vmcnt.  Flag seen =>
// data at LLC (stores drained before flag); barrier extends to all waves.
__global__ __launch_bounds__(256, 1) void lstm_scan(
    const f16* __restrict__ xpre_f, const f16* __restrict__ xpre_b,
    const float* __restrict__ whh_f, const float* __restrict__ whh_b,
    const int* __restrict__ lengths,
    f16* __restrict__ out,      // [BT, 2H]
    bf16* __restrict__ hbuf,    // [dir][parity][hi/lo][64][512]
    int* __restrict__ bar, int base) {
    __shared__ bf16 w_lo2[32][64][8];  // [slot=nt*16+c][lane][8] : lane-private
    __shared__ float gat[64][33];      // [batch][gate*8+u], stride 33
    __shared__ int len_s[64];

    const int dir = blockIdx.x >> 6;
    const int sl = blockIdx.x & 63;
    const int tid = threadIdx.x;
    const int wave = tid >> 6;
    const int lane = tid & 63;
    const int lrow = lane & 15;
    const int quad = lane >> 4;
    // wave-local gate mapping: thread -> (batch gb in wave's 16, unit-pair)
    const int gb = wave * 16 + (lane >> 2);
    const int up = lane & 3;
    const int u0 = up * 2;

    const f16* xpre = dir ? xpre_b : xpre_f;
    const float* whh = dir ? whh_b : whh_f;
    bf16* hb = hbuf + (size_t)dir * 2 * 2 * BB * HH;
    int* flags = bar + dir * 1024;   // 64 single-producer flags, 64B apart
    int* myflag = flags + sl * 16;

    // ---- stage w_hh slice: hi -> regs BH[nt][c], lo -> lane-private LDS.
    // B-frag for (nt,c): w row R=nt*16+lrow (gate g=R>>3, unit u=R&7),
    // k-cols c*32+quad*8..+8  <-  whh[(g*512 + sl*8 + u)][k]
    short8 BH[2][16];
#pragma unroll
    for (int nt = 0; nt < 2; ++nt) {
        int R = nt * 16 + lrow;
        const float* wr = whh + (size_t)((R >> 3) * HH + sl * 8 + (R & 7)) * HH + quad * 8;
#pragma unroll
        for (int c = 0; c < 16; ++c) {
            float4 v0 = *(const float4*)(wr + c * 32);
            float4 v1 = *(const float4*)(wr + c * 32 + 4);
            float vv[8] = {v0.x, v0.y, v0.z, v0.w, v1.x, v1.y, v1.z, v1.w};
            short8 h8, l8;
#pragma unroll
            for (int j = 0; j < 8; ++j) {
                bf16 h = __float2bfloat16(vv[j]);
                h8[j] = (short)__bfloat16_as_ushort(h);
                l8[j] = f2bs(vv[j] - __bfloat162float(h));
            }
            BH[nt][c] = h8;
            *(short8*)&w_lo2[nt * 16 + c][lane][0] = l8;
        }
    }
    if (tid < 64) len_s[tid] = lengths[tid];
    __syncthreads();

    // persistent per-thread recurrent state (2 hidden units each)
    float hr0 = 0.f, hr1 = 0.f, cr0 = 0.f, cr1 = 0.f;

    // prefetch xpre for s = 0 (len >= 1 always)
    float pr[2][4];
    {
        int len = len_s[gb];
        int ta = dir ? (len - 1) : 0;
        const f16* xp = xpre + (size_t)(gb * TT + ta) * 2048 + sl * 8 + u0;
        half2v g0 = *(const half2v*)(xp);
        half2v g1 = *(const half2v*)(xp + 512);
        half2v g2 = *(const half2v*)(xp + 1024);
        half2v g3 = *(const half2v*)(xp + 1536);
        pr[0][0] = (float)g0[0]; pr[1][0] = (float)g0[1];
        pr[0][1] = (float)g1[0]; pr[1][1] = (float)g1[1];
        pr[0][2] = (float)g2[0]; pr[1][2] = (float)g2[1];
        pr[0][3] = (float)g3[0]; pr[1][3] = (float)g3[1];
    }

    for (int s = 0; s < TT; ++s) {
        if (s > 0) {
            const int target = base + s;

            // ---- wave0-only readiness poll; barrier releases the block
            if (wave == 0) {
                int* fp = &flags[lane * 16];
                int v = __hip_atomic_load(fp, __ATOMIC_RELAXED,
                                          __HIP_MEMORY_SCOPE_AGENT);
                while (__ballot(v >= target) != ~0ull) {
                    __builtin_amdgcn_s_sleep(1);
                    v = __hip_atomic_load(fp, __ATOMIC_RELAXED,
                                          __HIP_MEMORY_SCOPE_AGENT);
                }
            }
            __syncthreads();
            __asm__ volatile("" ::: "memory");

            // ---- burst-issue ALL h loads: 32 x dwordx4, sc0 sc1
            const int b = wave * 16 + lrow;
            const char* hpb = (const char*)hb +
                (size_t)(((s & 1) ^ 1) * 2) * BB * HH * sizeof(bf16);
            const char* hib = hpb + b * 1024 + quad * 16;
            const char* lob = hib + BB * HH * sizeof(bf16);  // +64KB

            short8 AH[16], AL[16];
#pragma unroll
            for (int c = 0; c < 16; ++c) {
                asm volatile("global_load_dwordx4 %0, %1, off offset:%2 sc0 sc1"
                             : "=v"(AH[c]) : "v"(hib), "n"(c * 64));
                asm volatile("global_load_dwordx4 %0, %1, off offset:%2 sc0 sc1"
                             : "=v"(AL[c]) : "v"(lob), "n"(c * 64));
            }

            // 4 accumulator chains: (nt, c&1)
            f32x4 ac[2][2];
            ac[0][0] = (f32x4){0.f, 0.f, 0.f, 0.f};
            ac[0][1] = (f32x4){0.f, 0.f, 0.f, 0.f};
            ac[1][0] = (f32x4){0.f, 0.f, 0.f, 0.f};
            ac[1][1] = (f32x4){0.f, 0.f, 0.f, 0.f};

            // first half ready at vmcnt(16) (in-order completion counting)
            asm volatile("s_waitcnt vmcnt(16)" ::: "memory");
            __builtin_amdgcn_sched_barrier(0);
#pragma unroll
            for (int c = 0; c < 8; ++c) {
#pragma unroll
                for (int nt = 0; nt < 2; ++nt) {
                    short8 bll = *(const short8*)&w_lo2[nt * 16 + c][lane][0];
                    ac[nt][c & 1] = __builtin_amdgcn_mfma_f32_16x16x32_bf16(AH[c], BH[nt][c], ac[nt][c & 1], 0, 0, 0);
                    ac[nt][c & 1] = __builtin_amdgcn_mfma_f32_16x16x32_bf16(AL[c], BH[nt][c], ac[nt][c & 1], 0, 0, 0);
                    ac[nt][c & 1] = __builtin_amdgcn_mfma_f32_16x16x32_bf16(AH[c], bll, ac[nt][c & 1], 0, 0, 0);
                }
            }
            asm volatile("s_waitcnt vmcnt(0)" ::: "memory");
            __builtin_amdgcn_sched_barrier(0);
#pragma unroll
            for (int c = 8; c < 16; ++c) {
#pragma unroll
                for (int nt = 0; nt < 2; ++nt) {
                    short8 bll = *(const short8*)&w_lo2[nt * 16 + c][lane][0];
                    ac[nt][c & 1] = __builtin_amdgcn_mfma_f32_16x16x32_bf16(AH[c], BH[nt][c], ac[nt][c & 1], 0, 0, 0);
                    ac[nt][c & 1] = __builtin_amdgcn_mfma_f32_16x16x32_bf16(AL[c], BH[nt][c], ac[nt][c & 1], 0, 0, 0);
                    ac[nt][c & 1] = __builtin_amdgcn_mfma_f32_16x16x32_bf16(AH[c], bll, ac[nt][c & 1], 0, 0, 0);
                }
            }
            // acc -> gat (wave-local rows only); no block barrier needed:
            // each wave reads back only rows it wrote (rule #18 fence).
#pragma unroll
            for (int nt = 0; nt < 2; ++nt)
#pragma unroll
                for (int r = 0; r < 4; ++r)
                    gat[wave * 16 + quad * 4 + r][nt * 16 + lrow] =
                        ac[nt][0][r] + ac[nt][1][r];
            asm volatile("s_waitcnt lgkmcnt(0)" ::: "memory");
            __builtin_amdgcn_sched_barrier(0);
        }

        // ---- gate phase: thread handles (gb, units u0,u0+1), wave-local ----
        const int len = len_s[gb];
        const bool act = (s < len);
        if (act) {
            float z0[4], z1[4];
#pragma unroll
            for (int g = 0; g < 4; ++g) { z0[g] = pr[0][g]; z1[g] = pr[1][g]; }
            if (s > 0) {
#pragma unroll
                for (int g = 0; g < 4; ++g) {
                    z0[g] += gat[gb][g * 8 + u0];
                    z1[g] += gat[gb][g * 8 + u0 + 1];
                }
            }
            float i0 = sigm(z0[0]), f0 = sigm(z0[1]);
            float g0 = tanh_f(z0[2]), o0 = sigm(z0[3]);
            float i1 = sigm(z1[0]), f1 = sigm(z1[1]);
            float g1 = tanh_f(z1[2]), o1 = sigm(z1[3]);
            cr0 = f0 * cr0 + i0 * g0;
            cr1 = f1 * cr1 + i1 * g1;
            hr0 = o0 * tanh_f(cr0);
            hr1 = o1 * tanh_f(cr1);
        }
        // publish hi/lo packed (always; carried h for masked rows): 4B sc0sc1
        {
            bf16 bh0 = __float2bfloat16(hr0);
            bf16 bh1 = __float2bfloat16(hr1);
            unsigned int hw = (unsigned int)__bfloat16_as_ushort(bh0) |
                              ((unsigned int)__bfloat16_as_ushort(bh1) << 16);
            float r0 = hr0 - __bfloat162float(bh0);
            float r1 = hr1 - __bfloat162float(bh1);
            unsigned int lw = (unsigned int)(unsigned short)f2bs(r0) |
                              ((unsigned int)(unsigned short)f2bs(r1) << 16);
            char* hcb = (char*)hb + (size_t)((s & 1) * 2) * BB * HH * sizeof(bf16);
            char* pa = hcb + gb * 1024 + (sl * 8 + u0) * 2;
            char* pb = pa + BB * HH * sizeof(bf16);
            asm volatile("global_store_dword %0, %1, off sc0 sc1"
                         :: "v"(pa), "v"(hw) : "memory");
            asm volatile("global_store_dword %0, %1, off sc0 sc1"
                         :: "v"(pb), "v"(lw) : "memory");
        }
        asm volatile("s_waitcnt vmcnt(0)" ::: "memory");  // drain h-stores
        __syncthreads();

        // signal: one fire-and-forget monotonic atomic STORE per block
        if (tid == 0)
            __hip_atomic_store(myflag, base + s + 1, __ATOMIC_RELAXED,
                               __HIP_MEMORY_SCOPE_AGENT);

        // off the inter-block critical path: prefetch next xpre, then out store
        if (s + 1 < TT) {
            if (s + 1 < len) {
                int ta = dir ? (len - 2 - s) : (s + 1);
                const f16* xp = xpre + (size_t)(gb * TT + ta) * 2048 + sl * 8 + u0;
                half2v g0 = *(const half2v*)(xp);
                half2v g1 = *(const half2v*)(xp + 512);
                half2v g2 = *(const half2v*)(xp + 1024);
                half2v g3 = *(const half2v*)(xp + 1536);
                pr[0][0] = (float)g0[0]; pr[1][0] = (float)g0[1];
                pr[0][1] = (float)g1[0]; pr[1][1] = (float)g1[1];
                pr[0][2] = (float)g2[0]; pr[1][2] = (float)g2[1];
                pr[0][3] = (float)g3[0]; pr[1][3] = (float)g3[1];
            }
        }
        if (act) {
            int ta = dir ? (len - 1 - s) : s;
            half2v ov; ov[0] = (f16)hr0; ov[1] = (f16)hr1;
            *(half2v*)(out + (size_t)(gb * TT + ta) * 1024 + dir * 512 + sl * 8 + u0) = ov;
        } else {
            half2v zv; zv[0] = (f16)0.f; zv[1] = (f16)0.f;
            *(half2v*)(out + (size_t)(gb * TT + s) * 1024 + dir * 512 + sl * 8 + u0) = zv;
        }
    }
}

// ---------------------------------------------------------------------------
extern "C" void kernel_launch(void* const* d_in, const int* in_sizes, int n_in,
                              void* d_out, int out_size, void* d_ws, size_t ws_size,
                              hipStream_t stream) {
    const int* x = (const int*)d_in[0];
    const int* lengths = (const int*)d_in[1];
    const float* emb = (const float*)d_in[2];
    const float* w_ih_f1 = (const float*)d_in[3];
    const float* w_hh_f1 = (const float*)d_in[4];
    const float* b_f1 = (const float*)d_in[5];
    const float* w_ih_b1 = (const float*)d_in[6];
    const float* w_hh_b1 = (const float*)d_in[7];
    const float* b_b1 = (const float*)d_in[8];
    const float* w_ih_f2 = (const float*)d_in[9];
    const float* w_hh_f2 = (const float*)d_in[10];
    const float* b_f2 = (const float*)d_in[11];
    const float* w_ih_b2 = (const float*)d_in[12];
    const float* w_hh_b2 = (const float*)d_in[13];
    const float* b_b2 = (const float*)d_in[14];
    const float* cls_w = (const float*)d_in[15];
    const float* cls_b = (const float*)d_in[16];
    float* logits = (float*)d_out;

    // workspace layout (bytes) — max touched offset ~176 MB (proven envelope)
    char* ws = (char*)d_ws;
    int* bar = (int*)ws;                        // 0 .. 8 KB (2x64 flags, 64B apart)
    bf16* hbuf = (bf16*)(ws + 16384);           // 16 KB .. ~1.06 MB
    f16* e = (f16*)(ws + 2097152);              // 2 MB .. 10 MB
    f16* xpre_f = (f16*)(ws + 16777216);        // 16 MB .. 80 MB
    f16* xpre_b = (f16*)(ws + 83886080);        // 80 MB .. 144 MB
    f16* out1 = (f16*)(ws + 150994944);         // 144 MB .. 176 MB
    f16* out2 = out1;  // alias: out1 dead once layer-2 GEMMs complete

    bar_init<<<8, 256, 0, stream>>>(bar);
    embed_gather<<<BT / 4, 256, 0, stream>>>(x, emb, e);

    dim3 g1(BT / 128, 2048 / 128);
    gemm_bt<<<g1, 256, 0, stream>>>(e, w_ih_f1, b_f1, xpre_f, BT, 2048, EE);
    gemm_bt<<<g1, 256, 0, stream>>>(e, w_ih_b1, b_b1, xpre_b, BT, 2048, EE);
    lstm_scan<<<128, 256, 0, stream>>>(xpre_f, xpre_b, w_hh_f1, w_hh_b1,
                                       lengths, out1, hbuf, bar, 0);

    gemm_bt<<<g1, 256, 0, stream>>>(out1, w_ih_f2, b_f2, xpre_f, BT, 2048, 2 * HH);
    gemm_bt<<<g1, 256, 0, stream>>>(out1, w_ih_b2, b_b2, xpre_b, BT, 2048, 2 * HH);
    lstm_scan<<<128, 256, 0, stream>>>(xpre_f, xpre_b, w_hh_f2, w_hh_b2,
                                       lengths, out2, hbuf, bar, TT);

    cls_gemm<<<BT / 128, 256, 0, stream>>>(out2, cls_w, cls_b, logits);
}